// Round 1
// baseline (340.594 us; speedup 1.0000x reference)
//
#include <hip/hip_runtime.h>

// FeatureCorrelation: B=8192 rows x 3 steps x D=2048 fp32.
// Per row: 9 scalar reductions -> 12 weights -> 3 linear-combo outputs.
// Pure streaming: 201 MB in + 201 MB out; floor ~64 us @ 6.3 TB/s achievable.
//
// R4: wave-per-row restructure.
//  - Prior (320 us = 1.26 TB/s): 1 block/row, vmcnt(0) drain -> shuffle tree ->
//    LDS -> __syncthreads before any store; ~288 B/thread of MLP. Latency-bound.
//  - Now: 1 wave/row, 4 rows/block. No barriers, no LDS. 24 outstanding
//    global_load_dwordx4 per lane before first use; reduction is a pure
//    64-lane __shfl_xor butterfly. pos (24 KB) is L1-resident, cached loads.
//  - feat loads: NORMAL cached (m13's 6.29 TB/s pattern) -- NT loads dropped
//    as a suspect. NT kept on stores only (streamed, never re-read).

constexpr int D   = 2048;
constexpr int TPB = 256;                  // 4 waves = 4 rows per block
constexpr int RPB = TPB / 64;             // rows per block
constexpr int NC  = D / (64 * 4);         // fvec4 chunks per lane per vector = 8
constexpr float EPS_PD = 1e-6f;
constexpr float EPS_CS = 1e-8f;

using fvec4 = __attribute__((ext_vector_type(4))) float;

__global__ __launch_bounds__(TPB) void feat_corr_kernel(
    const float* __restrict__ feat,
    const float* __restrict__ pos,
    float* __restrict__ out,
    int B)
{
    const int wave = threadIdx.x >> 6;
    const int lane = threadIdx.x & 63;
    const int b    = blockIdx.x * RPB + wave;
    if (b >= B) return;                   // no barriers below -> early-exit safe

    const size_t row = (size_t)b * (3 * D);
    const fvec4* r1 = (const fvec4*)(feat + row);
    const fvec4* r2 = r1 + D / 4;
    const fvec4* r3 = r2 + D / 4;
    const fvec4* p1 = (const fvec4*)(pos);
    const fvec4* p2 = p1 + D / 4;
    const fvec4* p3 = p2 + D / 4;

    // ---- Load phase: 24 HBM loads in flight per lane (coalesced 1KB/wave/instr).
    fvec4 x1[NC], x2[NC], x3[NC];
#pragma unroll
    for (int j = 0; j < NC; ++j) x1[j] = r1[j * 64 + lane];
#pragma unroll
    for (int j = 0; j < NC; ++j) x2[j] = r2[j * 64 + lane];
#pragma unroll
    for (int j = 0; j < NC; ++j) x3[j] = r3[j * 64 + lane];

    // pos: tiny (24 KB), shared by all waves/blocks -> L1/L2 hits, normal loads.
#pragma unroll
    for (int j = 0; j < NC; ++j) {
        x1[j] += p1[j * 64 + lane];
        x2[j] += p2[j * 64 + lane];
        x3[j] += p3[j * 64 + lane];
    }

    // ---- 9 per-lane partial sums over 32 elements/vector.
    float n1s = 0.f, n2s = 0.f, n3s = 0.f;
    float d12 = 0.f, d13 = 0.f, d23 = 0.f;
    float s1  = 0.f, s2  = 0.f, s3  = 0.f;
#pragma unroll
    for (int j = 0; j < NC; ++j) {
#pragma unroll
        for (int k = 0; k < 4; ++k) {
            const float u = x1[j][k], w = x2[j][k], z = x3[j][k];
            n1s = fmaf(u, u, n1s);
            n2s = fmaf(w, w, n2s);
            n3s = fmaf(z, z, n3s);
            d12 = fmaf(u, w, d12);
            d13 = fmaf(u, z, d13);
            d23 = fmaf(w, z, d23);
            s1 += u; s2 += w; s3 += z;
        }
    }

    // ---- Full-wave butterfly reduction: every lane ends with the 9 totals.
    float vals[9] = {n1s, n2s, n3s, d12, d13, d23, s1, s2, s3};
#pragma unroll
    for (int off = 1; off < 64; off <<= 1) {
#pragma unroll
        for (int k = 0; k < 9; ++k)
            vals[k] += __shfl_xor(vals[k], off, 64);
    }

    const float N1s = vals[0], N2s = vals[1], N3s = vals[2];
    const float D12 = vals[3], D13 = vals[4], D23 = vals[5];
    const float S1  = vals[6], S2  = vals[7], S3  = vals[8];

    // ---- Weights (redundant per lane -- cheap scalar math).
    const float n1 = fmaxf(sqrtf(N1s), EPS_CS);
    const float n2 = fmaxf(sqrtf(N2s), EPS_CS);
    const float n3 = fmaxf(sqrtf(N3s), EPS_CS);

    const float c12 = 0.5f + 0.5f * (D12 / (n1 * n2));  // cosine terms (symmetric)
    const float c13 = 0.5f + 0.5f * (D13 / (n1 * n3));
    const float c23 = 0.5f + 0.5f * (D23 / (n2 * n3));

    const float sq12 = N1s + N2s - 2.f * D12;           // sum((fi-fj)^2)
    const float sq13 = N1s + N3s - 2.f * D13;
    const float sq23 = N2s + N3s - 2.f * D23;
    const float De2  = (float)D * EPS_PD * EPS_PD;

    // 1/(1+sqrt(sum((fi-fj+eps)^2))): eps inside the square -> sign-dependent
    auto wdist = [&](float sqd, float ssum) {
        return 1.0f / (1.0f + sqrtf(sqd + 2.f * EPS_PD * ssum + De2));
    };
    const float w12 = wdist(sq12, S1 - S2);
    const float w21 = wdist(sq12, S2 - S1);
    const float w13 = wdist(sq13, S1 - S3);
    const float w31 = wdist(sq13, S3 - S1);
    const float w23 = wdist(sq23, S2 - S3);
    const float w32 = wdist(sq23, S3 - S2);

    // o1 = f1 + (w12+c12) f2 + (w13+c13) f3
    // o2 = f2 + (w21+c12) f1 + (w23+c23) f3
    // o3 = f3 + (w31+c13) f1 + (w32+c23) f2
    const float g1b = w12 + c12, g1c = w13 + c13;
    const float g2a = w21 + c12, g2c = w23 + c23;
    const float g3a = w31 + c13, g3b = w32 + c23;

    fvec4* o1 = (fvec4*)(out + row);
    fvec4* o2 = o1 + D / 4;
    fvec4* o3 = o2 + D / 4;
#pragma unroll
    for (int j = 0; j < NC; ++j) {
        const int idx = j * 64 + lane;
        fvec4 q1 = x1[j] + g1b * x2[j] + g1c * x3[j];
        fvec4 q2 = x2[j] + g2a * x1[j] + g2c * x3[j];
        fvec4 q3 = x3[j] + g3a * x1[j] + g3b * x2[j];
        __builtin_nontemporal_store(q1, o1 + idx);   // streamed out: no L2 pollution
        __builtin_nontemporal_store(q2, o2 + idx);
        __builtin_nontemporal_store(q3, o3 + idx);
    }
}

extern "C" void kernel_launch(void* const* d_in, const int* in_sizes, int n_in,
                              void* d_out, int out_size, void* d_ws, size_t ws_size,
                              hipStream_t stream) {
    const float* feat = (const float*)d_in[0];
    const float* pos  = (const float*)d_in[1];
    float* out        = (float*)d_out;
    const int B = in_sizes[0] / (3 * D * (int)sizeof(float));  // bytes -> rows? see below
    // in_sizes semantics: element count in prior session (B computed as /(3*D)).
    // Keep prior-session semantics (it harness-verified at 320us):
    const int B_rows = in_sizes[0] / (3 * D);
    const int Buse   = (B_rows > 0) ? B_rows : B;
    const int grid   = (Buse + RPB - 1) / RPB;
    feat_corr_kernel<<<grid, TPB, 0, stream>>>(feat, pos, out, Buse);
}